// Round 1
// baseline (122.721 us; speedup 1.0000x reference)
//
#include <hip/hip_runtime.h>

#define N_PTS 8192
#define SEQ   2048
#define BATCH 4
#define KNEG  4
#define NK    32768   // N * K_NEG
#define N2    16384   // 2 * N
#define NACC  22

__device__ __forceinline__ float frcp(float x)  { return __builtin_amdgcn_rcpf(x); }
__device__ __forceinline__ float fsqrt_(float x){ return __builtin_amdgcn_sqrtf(x); }

// ---------------------------------------------------------------------------
// Kernel A: pairwise 2D forces.  grid = (jchunk=8, itile=8, batch=4), 256 thr.
// Each block stages one 256-wide j-tile (pos.x, pos.y, mass) in LDS; each
// thread owns one i and loops the tile.  Diagonal term has diff==0 exactly,
// so it contributes 0 without special-casing.  Partials merged by atomicAdd
// (8 contributors per address).
// ---------------------------------------------------------------------------
__global__ __launch_bounds__(256) void forces_kernel(
    const float* __restrict__ pos, const float* __restrict__ mass,
    const float* __restrict__ Gptr, const float* __restrict__ Rptr,
    float* __restrict__ out)
{
    const int tid = threadIdx.x;
    const int jc  = blockIdx.x;   // 0..7
    const int it  = blockIdx.y;   // 0..7
    const int b   = blockIdx.z;   // 0..3

    __shared__ float sx[256], sy[256], sm[256];
    const int j0 = jc * 256;
    {
        const int jb = b * SEQ + j0 + tid;
        sx[tid] = pos[jb * 2 + 0];
        sy[tid] = pos[jb * 2 + 1];
        sm[tid] = mass[jb];
    }
    const float Gv = fmaxf(Gptr[0], 0.0f);
    const float Rv = fmaxf(Rptr[0], 0.0f);
    const int   i     = it * 256 + tid;
    const int   ibase = b * SEQ + i;
    const float px = pos[ibase * 2 + 0];
    const float py = pos[ibase * 2 + 1];
    const float ci = Gv * mass[ibase];      // G+ * m_i
    __syncthreads();

    float fx = 0.0f, fy = 0.0f;
    #pragma unroll 4
    for (int j = 0; j < 256; ++j) {
        const float dx = sx[j] - px;        // diff = pos_j - pos_i
        const float dy = sy[j] - py;
        const float r2 = fmaf(dx, dx, fmaf(dy, dy, 1e-6f));
        const float r  = fsqrt_(r2);
        const float rp = r + 1e-9f;
        // (rep - att) / (r + eps), regrouped through reciprocals:
        float mor = -(ci * sm[j]) * frcp(r2 * rp);
        const float t = fmaf(-10.0f, r, 1.0f);      // 1 - r/0.1
        if (t > 0.0f) {                              // rare (r < 0.1)
            mor += (Rv * t) * frcp(fmaf(r2, r, 1e-9f) * rp);
        }
        fx = fmaf(mor, dx, fx);
        fy = fmaf(mor, dy, fy);
    }
    atomicAdd(&out[ibase * 2 + 0], fx);
    atomicAdd(&out[ibase * 2 + 1], fy);
}

// ---------------------------------------------------------------------------
// Kernel B: all loss reductions in one pass. 65536 threads; item idx covers:
//   always      : well_neg row idx            -> acc[3]
//   idx < 32768 : pe_pairwise_neg term        -> acc[1]
//   idx < 16384 : well_pos row + variance sums-> acc[2], acc[4..11], acc[12..19]
//   idx <  8192 : pe_pairwise_pos, mass, ke   -> acc[0], acc[20], acc[21]
// Block-reduced (wave shuffle + LDS) then one double atomicAdd per acc.
// ---------------------------------------------------------------------------
__device__ __forceinline__ float min_dist2(float4 a, float4 b, const float* __restrict__ wc)
{
    float best = 3.4e38f;
    #pragma unroll
    for (int w = 0; w < 16; ++w) {
        const float* c = &wc[w * 8];
        float d, s;
        d = a.x - c[0]; s = d * d;
        d = a.y - c[1]; s = fmaf(d, d, s);
        d = a.z - c[2]; s = fmaf(d, d, s);
        d = a.w - c[3]; s = fmaf(d, d, s);
        d = b.x - c[4]; s = fmaf(d, d, s);
        d = b.y - c[5]; s = fmaf(d, d, s);
        d = b.z - c[6]; s = fmaf(d, d, s);
        d = b.w - c[7]; s = fmaf(d, d, s);
        best = fminf(best, s);
    }
    return best;
}

__global__ __launch_bounds__(256) void loss_partials_kernel(
    const float* __restrict__ pos2,   // [N,2]
    const float* __restrict__ mass,   // [N]
    const float* __restrict__ vel,    // [N,2]
    const float* __restrict__ pos8,   // [N,8]
    const float* __restrict__ pp2,    // [N,2]
    const float* __restrict__ pp8,    // [N,8]
    const float* __restrict__ pmass,  // [N]
    const float* __restrict__ negp2,  // [NK,2]
    const float* __restrict__ negp8,  // [NK,8]
    const float* __restrict__ negm,   // [NK]
    const float* __restrict__ expm,   // [NK]
    const float* __restrict__ wellc,  // [16,8]
    double* __restrict__ wsacc)       // [22]
{
    __shared__ float wc[128];
    const int tid = threadIdx.x;
    if (tid < 128) wc[tid] = wellc[tid];
    __syncthreads();

    const int idx = blockIdx.x * 256 + tid;   // [0, 65536)

    double acc[NACC];
    #pragma unroll
    for (int k = 0; k < NACC; ++k) acc[k] = 0.0;

    {   // well_neg row: first NK rows are repeat(pos8, K), then neg_pos_8d
        const float* row = (idx < NK) ? (pos8 + (idx >> 2) * 8)
                                      : (negp8 + (idx - NK) * 8);
        const float4 a = ((const float4*)row)[0];
        const float4 b = ((const float4*)row)[1];
        acc[3] = (double)min_dist2(a, b, wc);
    }
    if (idx < NK) {   // pe_pairwise_neg
        const int i = idx >> 2;
        const float dx = pos2[i * 2 + 0] - negp2[idx * 2 + 0];
        const float dy = pos2[i * 2 + 1] - negp2[idx * 2 + 1];
        const float d  = fsqrt_(fmaf(dx, dx, dy * dy)) + 1e-9f;
        acc[1] = (double)(expm[idx] * negm[idx] / d);
    }
    if (idx < N2) {   // well_pos + variance over all_pos_8d
        const float* row = (idx < N_PTS) ? (pos8 + idx * 8)
                                         : (pp8 + (idx - N_PTS) * 8);
        const float4 a = ((const float4*)row)[0];
        const float4 b = ((const float4*)row)[1];
        acc[2] = (double)min_dist2(a, b, wc);
        acc[4]  = (double)a.x;  acc[12] = (double)(a.x * a.x);
        acc[5]  = (double)a.y;  acc[13] = (double)(a.y * a.y);
        acc[6]  = (double)a.z;  acc[14] = (double)(a.z * a.z);
        acc[7]  = (double)a.w;  acc[15] = (double)(a.w * a.w);
        acc[8]  = (double)b.x;  acc[16] = (double)(b.x * b.x);
        acc[9]  = (double)b.y;  acc[17] = (double)(b.y * b.y);
        acc[10] = (double)b.z;  acc[18] = (double)(b.z * b.z);
        acc[11] = (double)b.w;  acc[19] = (double)(b.w * b.w);
    }
    if (idx < N_PTS) {   // pe_pairwise_pos, mass sum, ke sum
        const float dx = pos2[idx * 2 + 0] - pp2[idx * 2 + 0];
        const float dy = pos2[idx * 2 + 1] - pp2[idx * 2 + 1];
        const float d  = fsqrt_(fmaf(dx, dx, dy * dy)) + 1e-9f;
        acc[0]  = (double)(mass[idx] * pmass[idx] / d);
        acc[20] = (double)mass[idx];
        const float vx = vel[idx * 2 + 0];
        const float vy = vel[idx * 2 + 1];
        acc[21] = (double)fmaf(vx, vx, vy * vy);
    }

    // block reduction: wave64 shuffle, then cross-wave via LDS
    __shared__ double red[4][NACC];
    const int lane = tid & 63, wid = tid >> 6;
    #pragma unroll
    for (int k = 0; k < NACC; ++k) {
        double v = acc[k];
        for (int off = 32; off > 0; off >>= 1) v += __shfl_down(v, off, 64);
        if (lane == 0) red[wid][k] = v;
    }
    __syncthreads();
    if (tid < NACC) {
        const double s = red[0][tid] + red[1][tid] + red[2][tid] + red[3][tid];
        atomicAdd(&wsacc[tid], s);
    }
}

// ---------------------------------------------------------------------------
// Kernel C: finalize loss in fp64 (mirrors reference structure exactly).
// ---------------------------------------------------------------------------
__global__ void finalize_kernel(const double* __restrict__ s,
                                const float* __restrict__ Gptr,
                                const float* __restrict__ wsPtr,
                                const float* __restrict__ tPtr,
                                const float* __restrict__ ecPtr,
                                float* __restrict__ out)
{
    if (threadIdx.x == 0 && blockIdx.x == 0) {
        const double Gp  = fmax((double)Gptr[0], 0.0);
        const double wsp = fmax((double)wsPtr[0], 0.0);
        const double T   = fmax((double)tPtr[0], 0.0);
        const double ec  = fmax((double)ecPtr[0], 0.0);
        const double Nd = 8192.0, NKd = 32768.0, N2d = 16384.0, NK2d = 65536.0;

        const double U_pos = -Gp * s[0] / Nd  + wsp * s[2] / N2d;
        const double U_neg = -Gp * s[1] / NKd + wsp * s[3] / NK2d;

        double var = 0.0;
        for (int d = 0; d < 8; ++d) {
            const double sx = s[4 + d], sxx = s[12 + d];
            var += (sxx - sx * sx / N2d) / (N2d - 1.0);   // ddof=1
        }
        var *= 0.125;
        const double ent = T * ec * var;
        const double Fp = U_pos - ent, Fn = U_neg - ent;
        double fel = 1.0 + Fp - Fn;            // MARGIN + F_pos - F_neg
        if (fel < 0.0) fel = 0.0;
        const double ke_loss = 1e-3 * 0.5 * (s[20] / Nd) * (s[21] / Nd);
        out[16384] = (float)(fel + ke_loss);
    }
}

// ---------------------------------------------------------------------------
extern "C" void kernel_launch(void* const* d_in, const int* in_sizes, int n_in,
                              void* d_out, int out_size, void* d_ws, size_t ws_size,
                              hipStream_t stream)
{
    const float* pos   = (const float*)d_in[0];   // [4,2048,2] == [N,2]
    const float* mass  = (const float*)d_in[1];   // [4,2048,1] == [N]
    const float* vel   = (const float*)d_in[2];
    const float* pos8  = (const float*)d_in[3];
    const float* pp2   = (const float*)d_in[4];
    const float* pp8   = (const float*)d_in[5];
    const float* pmass = (const float*)d_in[6];
    const float* negp2 = (const float*)d_in[7];
    const float* negp8 = (const float*)d_in[8];
    const float* negm  = (const float*)d_in[9];
    const float* expm  = (const float*)d_in[10];
    const float* Gp    = (const float*)d_in[11];
    const float* Rp    = (const float*)d_in[12];
    const float* wellc = (const float*)d_in[13];
    const float* wstr  = (const float*)d_in[14];
    const float* temp  = (const float*)d_in[15];
    const float* ecoef = (const float*)d_in[16];

    float*  out = (float*)d_out;
    double* acc = (double*)d_ws;

    // d_out / d_ws are poisoned 0xAA before every launch — zero what we use.
    hipMemsetAsync(d_out, 0, (size_t)out_size * sizeof(float), stream);
    hipMemsetAsync(d_ws, 0, NACC * sizeof(double), stream);

    forces_kernel<<<dim3(8, 8, 4), 256, 0, stream>>>(pos, mass, Gp, Rp, out);
    loss_partials_kernel<<<256, 256, 0, stream>>>(pos, mass, vel, pos8, pp2, pp8,
                                                  pmass, negp2, negp8, negm, expm,
                                                  wellc, acc);
    finalize_kernel<<<1, 64, 0, stream>>>(acc, Gp, wstr, temp, ecoef, out);
}

// Round 2
// 107.578 us; speedup vs baseline: 1.1408x; 1.1408x over previous
//
#include <hip/hip_runtime.h>

#define SEQ    2048
#define N_PTS  8192
#define NK     32768   // N * K_NEG
#define N2     16384   // 2 * N
#define NACC   22
#define NLOSSBLK 256
#define SLOT_DOUBLES (NLOSSBLK * NACC)      // 5632 doubles
#define CTR_OFFSET   (SLOT_DOUBLES * 8)     // byte offset of ticket counter in d_ws

__device__ __forceinline__ float frcp(float x)  { return __builtin_amdgcn_rcpf(x); }
__device__ __forceinline__ float fsqrt_(float x){ return __builtin_amdgcn_sqrtf(x); }

__device__ __forceinline__ float min_dist2(float4 a, float4 b, const float* __restrict__ wc)
{
    float best = 3.4e38f;
    #pragma unroll
    for (int w = 0; w < 16; ++w) {
        const float* c = &wc[w * 8];
        float d, s;
        d = a.x - c[0]; s = d * d;
        d = a.y - c[1]; s = fmaf(d, d, s);
        d = a.z - c[2]; s = fmaf(d, d, s);
        d = a.w - c[3]; s = fmaf(d, d, s);
        d = b.x - c[4]; s = fmaf(d, d, s);
        d = b.y - c[5]; s = fmaf(d, d, s);
        d = b.z - c[6]; s = fmaf(d, d, s);
        d = b.w - c[7]; s = fmaf(d, d, s);
        best = fminf(best, s);
    }
    return best;
}

// ---------------------------------------------------------------------------
// One fused kernel, 512 blocks x 256 threads:
//   blocks 0..255   : pairwise forces. block = (b, 32-wide i-tile); threads =
//                     32 i x 8 j-slices over the whole 2048-pt row in LDS;
//                     LDS-reduce 8 partials per i, direct store (no atomics,
//                     no d_out memset needed).
//   blocks 256..511 : loss partial sums -> per-block slot in d_ws (no init
//                     needed). Last-arriving loss block (device-scope ticket)
//                     reduces all slots and writes the final loss.
// ---------------------------------------------------------------------------
__global__ __launch_bounds__(256) void fused_kernel(
    const float* __restrict__ pos,    // [N,2]
    const float* __restrict__ mass,   // [N]
    const float* __restrict__ vel,    // [N,2]
    const float* __restrict__ pos8,   // [N,8]
    const float* __restrict__ pp2,    // [N,2]
    const float* __restrict__ pp8,    // [N,8]
    const float* __restrict__ pmass,  // [N]
    const float* __restrict__ negp2,  // [NK,2]
    const float* __restrict__ negp8,  // [NK,8]
    const float* __restrict__ negm,   // [NK]
    const float* __restrict__ expm,   // [NK]
    const float* __restrict__ Gptr,
    const float* __restrict__ Rptr,
    const float* __restrict__ wellc,  // [16,8]
    const float* __restrict__ wstr,
    const float* __restrict__ tPtr,
    const float* __restrict__ ecPtr,
    float* __restrict__ out,          // [16385]
    double* __restrict__ slots,       // [256][22] in d_ws
    unsigned int* __restrict__ ctr)   // ticket counter in d_ws (memset to 0)
{
    const int tid = threadIdx.x;
    const int blk = blockIdx.x;

    if (blk < 256) {
        // ----------------------------- FORCES -----------------------------
        __shared__ float sx[SEQ], sy[SEQ], sm[SEQ];   // 24 KB
        __shared__ float rf[2][8][32];

        const int b  = blk >> 6;          // 0..3
        const int it = blk & 63;          // 0..63  (32-wide i tile)
        const int rowbase = b * SEQ;

        const float2* p2 = (const float2*)pos;
        for (int k = tid; k < SEQ; k += 256) {
            const float2 v = p2[rowbase + k];
            sx[k] = v.x; sy[k] = v.y;
            sm[k] = mass[rowbase + k];
        }
        const float Gv = fmaxf(Gptr[0], 0.0f);
        const float Rv = fmaxf(Rptr[0], 0.0f);
        __syncthreads();

        const int il = tid & 31;          // i within tile
        const int js = tid >> 5;          // j-slice 0..7
        const int iloc = it * 32 + il;    // i within batch row
        const float px = sx[iloc];
        const float py = sy[iloc];
        const float ci = Gv * sm[iloc];   // G+ * m_i

        float fx = 0.0f, fy = 0.0f;
        const int j0 = js * 256;
        #pragma unroll 4
        for (int jj = 0; jj < 256; ++jj) {
            const int j = j0 + jj;
            const float dx = sx[j] - px;         // diff = pos_j - pos_i
            const float dy = sy[j] - py;
            const float r2 = fmaf(dx, dx, fmaf(dy, dy, 1e-6f));
            const float r  = fsqrt_(r2);
            const float rp = r + 1e-9f;
            float mor = -(ci * sm[j]) * frcp(r2 * rp);
            const float t = fmaf(-10.0f, r, 1.0f);   // 1 - r/0.1
            if (t > 0.0f) {                          // rare (r < 0.1)
                mor += (Rv * t) * frcp(fmaf(r2, r, 1e-9f) * rp);
            }
            fx = fmaf(mor, dx, fx);
            fy = fmaf(mor, dy, fy);
        }
        rf[0][js][il] = fx;
        rf[1][js][il] = fy;
        __syncthreads();
        if (tid < 64) {
            const int comp = tid >> 5, i2 = tid & 31;
            float s = 0.0f;
            #pragma unroll
            for (int q = 0; q < 8; ++q) s += rf[comp][q][i2];
            out[(rowbase + it * 32 + i2) * 2 + comp] = s;
        }
        return;
    }

    // ------------------------------- LOSS ---------------------------------
    __shared__ float  wc[128];
    __shared__ double red[4][NACC];
    __shared__ int    lastflag;

    if (tid < 128) wc[tid] = wellc[tid];
    if (tid == 0)  lastflag = 0;
    __syncthreads();

    const int lb  = blk - 256;            // 0..255
    const int idx = lb * 256 + tid;       // [0, 65536)

    double acc[NACC];
    #pragma unroll
    for (int k = 0; k < NACC; ++k) acc[k] = 0.0;

    {   // well_neg row: first NK rows are repeat(pos8, K), then neg_pos_8d
        const float* row = (idx < NK) ? (pos8 + (idx >> 2) * 8)
                                      : (negp8 + (idx - NK) * 8);
        const float4 a = ((const float4*)row)[0];
        const float4 b = ((const float4*)row)[1];
        acc[3] = (double)min_dist2(a, b, wc);
    }
    if (idx < NK) {   // pe_pairwise_neg
        const int i = idx >> 2;
        const float dx = pos[i * 2 + 0] - negp2[idx * 2 + 0];
        const float dy = pos[i * 2 + 1] - negp2[idx * 2 + 1];
        const float d  = fsqrt_(fmaf(dx, dx, dy * dy)) + 1e-9f;
        acc[1] = (double)(expm[idx] * negm[idx] / d);
    }
    if (idx < N2) {   // well_pos + variance sums over all_pos_8d
        const float* row = (idx < N_PTS) ? (pos8 + idx * 8)
                                         : (pp8 + (idx - N_PTS) * 8);
        const float4 a = ((const float4*)row)[0];
        const float4 b = ((const float4*)row)[1];
        acc[2] = (double)min_dist2(a, b, wc);
        acc[4]  = (double)a.x;  acc[12] = (double)(a.x * a.x);
        acc[5]  = (double)a.y;  acc[13] = (double)(a.y * a.y);
        acc[6]  = (double)a.z;  acc[14] = (double)(a.z * a.z);
        acc[7]  = (double)a.w;  acc[15] = (double)(a.w * a.w);
        acc[8]  = (double)b.x;  acc[16] = (double)(b.x * b.x);
        acc[9]  = (double)b.y;  acc[17] = (double)(b.y * b.y);
        acc[10] = (double)b.z;  acc[18] = (double)(b.z * b.z);
        acc[11] = (double)b.w;  acc[19] = (double)(b.w * b.w);
    }
    if (idx < N_PTS) {   // pe_pairwise_pos, mass sum, ke sum
        const float dx = pos[idx * 2 + 0] - pp2[idx * 2 + 0];
        const float dy = pos[idx * 2 + 1] - pp2[idx * 2 + 1];
        const float d  = fsqrt_(fmaf(dx, dx, dy * dy)) + 1e-9f;
        acc[0]  = (double)(mass[idx] * pmass[idx] / d);
        acc[20] = (double)mass[idx];
        const float vx = vel[idx * 2 + 0];
        const float vy = vel[idx * 2 + 1];
        acc[21] = (double)fmaf(vx, vx, vy * vy);
    }

    // block reduction: wave64 shuffle, then cross-wave via LDS
    const int lane = tid & 63, wid = tid >> 6;
    #pragma unroll
    for (int k = 0; k < NACC; ++k) {
        double v = acc[k];
        for (int off = 32; off > 0; off >>= 1) v += __shfl_down(v, off, 64);
        if (lane == 0) red[wid][k] = v;
    }
    __syncthreads();
    if (tid < NACC) {
        slots[lb * NACC + tid] = red[0][tid] + red[1][tid] + red[2][tid] + red[3][tid];
    }
    __syncthreads();                       // slot writes done (block-wide)
    if (tid == 0) {
        __threadfence();                   // release: publish slots
        const unsigned int ticket = atomicAdd(ctr, 1u);
        if (ticket == NLOSSBLK - 1) lastflag = 1;
    }
    __syncthreads();
    if (!lastflag) return;

    // --------- last loss block: reduce all slots + finalize loss ----------
    __threadfence();                       // acquire: see other blocks' slots
    #pragma unroll
    for (int k = 0; k < NACC; ++k) {
        double v = slots[tid * NACC + k];  // tid indexes the 256 slots
        for (int off = 32; off > 0; off >>= 1) v += __shfl_down(v, off, 64);
        if (lane == 0) red[wid][k] = v;
    }
    __syncthreads();
    if (tid == 0) {
        double s[NACC];
        #pragma unroll
        for (int k = 0; k < NACC; ++k)
            s[k] = red[0][k] + red[1][k] + red[2][k] + red[3][k];

        const double Gp  = fmax((double)Gptr[0], 0.0);
        const double wsp = fmax((double)wstr[0], 0.0);
        const double T   = fmax((double)tPtr[0], 0.0);
        const double ec  = fmax((double)ecPtr[0], 0.0);
        const double Nd = 8192.0, NKd = 32768.0, N2d = 16384.0, NK2d = 65536.0;

        const double U_pos = -Gp * s[0] / Nd  + wsp * s[2] / N2d;
        const double U_neg = -Gp * s[1] / NKd + wsp * s[3] / NK2d;

        double var = 0.0;
        for (int d = 0; d < 8; ++d) {
            const double sx_ = s[4 + d], sxx = s[12 + d];
            var += (sxx - sx_ * sx_ / N2d) / (N2d - 1.0);   // ddof=1
        }
        var *= 0.125;
        const double ent = T * ec * var;
        const double Fp = U_pos - ent, Fn = U_neg - ent;
        double fel = 1.0 + Fp - Fn;            // MARGIN + F_pos - F_neg
        if (fel < 0.0) fel = 0.0;
        const double ke_loss = 1e-3 * 0.5 * (s[20] / Nd) * (s[21] / Nd);
        out[16384] = (float)(fel + ke_loss);
    }
}

// ---------------------------------------------------------------------------
extern "C" void kernel_launch(void* const* d_in, const int* in_sizes, int n_in,
                              void* d_out, int out_size, void* d_ws, size_t ws_size,
                              hipStream_t stream)
{
    const float* pos   = (const float*)d_in[0];
    const float* mass  = (const float*)d_in[1];
    const float* vel   = (const float*)d_in[2];
    const float* pos8  = (const float*)d_in[3];
    const float* pp2   = (const float*)d_in[4];
    const float* pp8   = (const float*)d_in[5];
    const float* pmass = (const float*)d_in[6];
    const float* negp2 = (const float*)d_in[7];
    const float* negp8 = (const float*)d_in[8];
    const float* negm  = (const float*)d_in[9];
    const float* expm  = (const float*)d_in[10];
    const float* Gp    = (const float*)d_in[11];
    const float* Rp    = (const float*)d_in[12];
    const float* wellc = (const float*)d_in[13];
    const float* wstr  = (const float*)d_in[14];
    const float* temp  = (const float*)d_in[15];
    const float* ecoef = (const float*)d_in[16];

    float*        out   = (float*)d_out;
    double*       slots = (double*)d_ws;
    unsigned int* ctr   = (unsigned int*)((char*)d_ws + CTR_OFFSET);

    // d_ws is poisoned 0xAA before every launch — only the ticket counter
    // needs zeroing (slots are written before they are read).
    hipMemsetAsync(ctr, 0, sizeof(unsigned int), stream);

    fused_kernel<<<512, 256, 0, stream>>>(pos, mass, vel, pos8, pp2, pp8, pmass,
                                          negp2, negp8, negm, expm, Gp, Rp,
                                          wellc, wstr, temp, ecoef,
                                          out, slots, ctr);
}